// Round 8
// baseline (1625.901 us; speedup 1.0000x reference)
//
#include <hip/hip_runtime.h>
#include <cstddef>

#define T_LEN 4096
#define EMB 768
#define NH 12
#define HD 64
#define WIN 512
#define PBW 576   // compact band width per row (64-chunk + 4 pairs x 128)

#define GBM 128
#define GBN 128
#define GBK 16

// ---------------- 128x128 f32 GEMM block body: C[4096,768] = A[4096,768] @ B[768,768].
// 8x8 microtile, register-prefetch double buffer. Called by the fused kernels.
__device__ __forceinline__ void gemm_128(const float* __restrict__ A,
                                         const float* __restrict__ B,
                                         float* __restrict__ C,
                                         int bm, int bn, int tid) {
    __shared__ float As[GBK][GBM + 4];   // A transposed: [k][m]
    __shared__ float Bs[GBK][GBN + 4];   // B row-major:  [k][n]

    const int ty = (tid >> 4) << 2;
    const int tx = (tid & 15) << 2;

    const int ar = tid >> 1;
    const int ac = (tid & 1) << 3;
    const int br = tid >> 4;
    const int bc = (tid & 15) << 3;

    float acc[8][8] = {};

    float4 pa0 = *(const float4*)&A[(size_t)(bm + ar) * EMB + ac];
    float4 pa1 = *(const float4*)&A[(size_t)(bm + ar) * EMB + ac + 4];
    float4 pb0 = *(const float4*)&B[(size_t)br * EMB + bn + bc];
    float4 pb1 = *(const float4*)&B[(size_t)br * EMB + bn + bc + 4];

    for (int k0 = 0; k0 < EMB; k0 += GBK) {
        As[ac + 0][ar] = pa0.x; As[ac + 1][ar] = pa0.y; As[ac + 2][ar] = pa0.z; As[ac + 3][ar] = pa0.w;
        As[ac + 4][ar] = pa1.x; As[ac + 5][ar] = pa1.y; As[ac + 6][ar] = pa1.z; As[ac + 7][ar] = pa1.w;
        *(float4*)&Bs[br][bc]     = pb0;
        *(float4*)&Bs[br][bc + 4] = pb1;
        __syncthreads();
        if (k0 + GBK < EMB) {
            pa0 = *(const float4*)&A[(size_t)(bm + ar) * EMB + k0 + GBK + ac];
            pa1 = *(const float4*)&A[(size_t)(bm + ar) * EMB + k0 + GBK + ac + 4];
            pb0 = *(const float4*)&B[(size_t)(k0 + GBK + br) * EMB + bn + bc];
            pb1 = *(const float4*)&B[(size_t)(k0 + GBK + br) * EMB + bn + bc + 4];
        }
#pragma unroll
        for (int k = 0; k < GBK; ++k) {
            const float4 a0v = *(const float4*)&As[k][ty];
            const float4 a1v = *(const float4*)&As[k][ty + 64];
            const float4 b0v = *(const float4*)&Bs[k][tx];
            const float4 b1v = *(const float4*)&Bs[k][tx + 64];
            const float av[8] = {a0v.x, a0v.y, a0v.z, a0v.w, a1v.x, a1v.y, a1v.z, a1v.w};
            const float bv[8] = {b0v.x, b0v.y, b0v.z, b0v.w, b1v.x, b1v.y, b1v.z, b1v.w};
#pragma unroll
            for (int i = 0; i < 8; ++i)
#pragma unroll
                for (int j = 0; j < 8; ++j)
                    acc[i][j] += av[i] * bv[j];
        }
        __syncthreads();
    }
#pragma unroll
    for (int i = 0; i < 8; ++i) {
        const int r = bm + ty + ((i < 4) ? i : (60 + i));
        *(float4*)&C[(size_t)r * EMB + bn + tx]      = make_float4(acc[i][0], acc[i][1], acc[i][2], acc[i][3]);
        *(float4*)&C[(size_t)r * EMB + bn + tx + 64] = make_float4(acc[i][4], acc[i][5], acc[i][6], acc[i][7]);
    }
}

// ---------------- fused: QKV projections (576) + out-of-band zero-fill (192) + dbias (12).
// dbias uses d_raw[h][t] = x[t]·(Wk@u_h), so it only needs inputs — fully overlapped.
__global__ __launch_bounds__(256) void qkv_zero_kernel(const float* __restrict__ x,
                                                       const float* __restrict__ Wq,
                                                       const float* __restrict__ Wk,
                                                       const float* __restrict__ Wv,
                                                       const float* __restrict__ u,
                                                       float* __restrict__ Qb,
                                                       float* __restrict__ Kb,
                                                       float* __restrict__ Vb,
                                                       float* __restrict__ attn,
                                                       float* __restrict__ d_bias) {
    const int bid = blockIdx.x;
    const int tid = threadIdx.x;
    if (bid < 576) {
        const int z = bid / 192;
        const int r = bid % 192;
        const int bm = (r / 6) * GBM;
        const int bn = (r % 6) * GBN;
        const float* B = (z == 0) ? Wq : (z == 1) ? Wk : Wv;
        float* C = (z == 0) ? Qb : (z == 1) ? Kb : Vb;
        gemm_128(x, B, C, bm, bn, tid);
    } else if (bid < 768) {
        const int zb = bid - 576;          // 0..191
        const int rr0 = tid >> 6;          // 0..3
        const int ln = tid & 63;
        const float4 z4 = make_float4(0.f, 0.f, 0.f, 0.f);
        for (int k = 0; k < 4; ++k) {
            const int p = zb + 192 * k;    // 0..767 (h, tile) pairs
            const int h = p % NH;
            const int t0 = (p / NH) << 6;
            const int bl = (t0 >= WIN) ? (t0 - WIN) : 0;   // left zero bound (mult of 64)
            const int br = t0 + 64;                        // right zero start
            for (int rr = rr0; rr < 64; rr += 4) {
                float* arow = attn + ((size_t)(h * T_LEN + t0 + rr)) * T_LEN;
                for (int c = ln << 2; c < bl; c += 256)
                    *(float4*)&arow[c] = z4;
                for (int c = br + (ln << 2); c < T_LEN; c += 256)
                    *(float4*)&arow[c] = z4;
            }
        }
    } else {
        // dbias for head h = bid-768: wku = Wk @ u_h; dr[t] = x[t]·wku; subtract mean.
        const int h = bid - 768;
        __shared__ __align__(16) float us[HD];
        __shared__ __align__(16) float wku[EMB];
        __shared__ float dr[T_LEN];
        __shared__ float red[256];
        if (tid < HD) us[tid] = u[h * HD + tid];
        __syncthreads();
        const float4* u4 = (const float4*)us;
        for (int e = tid; e < EMB; e += 256) {
            const float4* Wp = (const float4*)&Wk[(size_t)e * EMB + h * HD];
            float a = 0.f;
#pragma unroll
            for (int i = 0; i < HD / 4; ++i) {
                float4 w4 = Wp[i];
                float4 uu = u4[i];
                a += w4.x * uu.x + w4.y * uu.y + w4.z * uu.z + w4.w * uu.w;
            }
            wku[e] = a;
        }
        __syncthreads();
        const float4* wk4 = (const float4*)wku;
        float lsum = 0.f;
        for (int t = tid; t < T_LEN; t += 256) {
            const float4* xp = (const float4*)&x[(size_t)t * EMB];
            float a = 0.f;
#pragma unroll 8
            for (int i = 0; i < EMB / 4; ++i) {
                float4 xv = xp[i];
                float4 wv = wk4[i];
                a += xv.x * wv.x + xv.y * wv.y + xv.z * wv.z + xv.w * wv.w;
            }
            dr[t] = a;
            lsum += a;
        }
        red[tid] = lsum;
        __syncthreads();
        for (int off = 128; off > 0; off >>= 1) {
            if (tid < off) red[tid] += red[tid + off];
            __syncthreads();
        }
        const float mean = red[0] * (1.0f / (float)T_LEN);
        __syncthreads();
        for (int t = tid; t < T_LEN; t += 256)
            d_bias[h * T_LEN + t] = dr[t] - mean;
    }
}

// ---------------- banded attention: leading 64-chunk + 4 pair-chunks (window = exactly
// [t0-512, t0+64), 576 cols). Flash softmax; p stored compactly into Pb[h][t][576]
// (step-local max scaling); per-step factors exp(m_step - m_final)/den into Fb[h][t][5].
__global__ __launch_bounds__(256) void attn_band_kernel(const float* __restrict__ Q,
                                                        const float* __restrict__ K,
                                                        const float* __restrict__ V,
                                                        const float* __restrict__ d_bias,
                                                        const float* __restrict__ gates,
                                                        float* __restrict__ Pb,
                                                        float* __restrict__ Fb,
                                                        float* __restrict__ ctx) {
    const int t0  = blockIdx.x << 6;
    const int h   = blockIdx.y;
    const int tid = threadIdx.x;
    const int cg  = tid & 15;          // col group 0..15
    const int tm  = (tid >> 4) << 2;   // row base 0..60
    const int tn4 = cg << 2;           // col base within each 64-half

    const int lm = tid >> 2;           // tile/chunk staging: row 0..63
    const int lk = (tid & 3) << 4;     // tile/chunk staging: col base {0,16,32,48}
    const int sr = tid >> 1;           // pair staging: row 0..127
    const int sc = (tid & 1) << 5;     // pair staging: col base {0,32}

    __shared__ __align__(16) float QT[64][68];   // Q tile transposed [k][m]
    __shared__ __align__(16) float KT[64][68];   // K tile transposed [k][m]
    __shared__ __align__(16) float Bc[64][136];  // K/Q staging; aliased as PT[128][68]
    __shared__ float cmf[5][64];                 // per-step per-row running max
    __shared__ float rmf[64], idvf[64];
    float* __restrict__ Bp = &Bc[0][0];

    // per-head gate softmax (fold 1/sqrt(64) into w_std/w_rec)
    const float g0 = gates[h * 3 + 0];
    const float g1 = gates[h * 3 + 1];
    const float g2 = gates[h * 3 + 2];
    const float gm = fmaxf(g0, fmaxf(g1, g2));
    const float e0 = __expf(g0 - gm), e1 = __expf(g1 - gm), e2 = __expf(g2 - gm);
    const float gi = 1.0f / (e0 + e1 + e2);
    const float w_std = e0 * gi * 0.125f;
    const float w_rec = e1 * gi * 0.125f;
    const float w_disc = e2 * gi;

    // stage t-tile Q and K, transposed [k][m]
    {
        const float* Qp = Q + (size_t)(t0 + lm) * EMB + h * HD + lk;
        const float* Kp = K + (size_t)(t0 + lm) * EMB + h * HD + lk;
#pragma unroll
        for (int it = 0; it < 4; ++it) {
            float4 a = *(const float4*)(Qp + 4 * it);
            QT[lk + 4 * it + 0][lm] = a.x;
            QT[lk + 4 * it + 1][lm] = a.y;
            QT[lk + 4 * it + 2][lm] = a.z;
            QT[lk + 4 * it + 3][lm] = a.w;
            float4 b = *(const float4*)(Kp + 4 * it);
            KT[lk + 4 * it + 0][lm] = b.x;
            KT[lk + 4 * it + 1][lm] = b.y;
            KT[lk + 4 * it + 2][lm] = b.z;
            KT[lk + 4 * it + 3][lm] = b.w;
        }
    }

    float rm[4], rden[4], acc[4][4];
#pragma unroll
    for (int i = 0; i < 4; ++i) {
        rm[i] = -1e30f;
        rden[i] = 0.f;
#pragma unroll
        for (int j = 0; j < 4; ++j) acc[i][j] = 0.f;
    }

    // ======== leading 64-chunk: cols [t0-512, t0-448), exists iff t0 >= 512 ========
    if (t0 >= WIN) {
        const int s0 = t0 - WIN;
        // stage K-chunk transposed into Bc[k][0..63]
        {
            const float* Kp = K + (size_t)(s0 + lm) * EMB + h * HD + lk;
#pragma unroll
            for (int it = 0; it < 4; ++it) {
                float4 b = *(const float4*)(Kp + 4 * it);
                Bc[lk + 4 * it + 0][lm] = b.x;
                Bc[lk + 4 * it + 1][lm] = b.y;
                Bc[lk + 4 * it + 2][lm] = b.z;
                Bc[lk + 4 * it + 3][lm] = b.w;
            }
        }
        __syncthreads();   // also publishes QT/KT
        float m1c[4][4] = {};
#pragma unroll 8
        for (int k = 0; k < 64; ++k) {
            const float4 a4 = *(const float4*)&QT[k][tm];
            const float4 b0 = *(const float4*)&Bc[k][tn4];
            const float av[4] = {a4.x, a4.y, a4.z, a4.w};
            const float bv[4] = {b0.x, b0.y, b0.z, b0.w};
#pragma unroll
            for (int i = 0; i < 4; ++i)
#pragma unroll
                for (int j = 0; j < 4; ++j)
                    m1c[i][j] += av[i] * bv[j];
        }
        __syncthreads();
        // stage Q-chunk transposed
        {
            const float* Qp = Q + (size_t)(s0 + lm) * EMB + h * HD + lk;
#pragma unroll
            for (int it = 0; it < 4; ++it) {
                float4 b = *(const float4*)(Qp + 4 * it);
                Bc[lk + 4 * it + 0][lm] = b.x;
                Bc[lk + 4 * it + 1][lm] = b.y;
                Bc[lk + 4 * it + 2][lm] = b.z;
                Bc[lk + 4 * it + 3][lm] = b.w;
            }
        }
        __syncthreads();
        float m2c[4][4] = {};
#pragma unroll 8
        for (int k = 0; k < 64; ++k) {
            const float4 a4 = *(const float4*)&KT[k][tm];
            const float4 b0 = *(const float4*)&Bc[k][tn4];
            const float av[4] = {a4.x, a4.y, a4.z, a4.w};
            const float bv[4] = {b0.x, b0.y, b0.z, b0.w};
#pragma unroll
            for (int i = 0; i < 4; ++i)
#pragma unroll
                for (int j = 0; j < 4; ++j)
                    m2c[i][j] += av[i] * bv[j];
        }
        // logits + mask (s >= 0 and s <= t always hold here; s >= t-512 is the live edge)
        const float4 db = *(const float4*)&d_bias[h * T_LEN + s0 + tn4];
        const float dbv[4] = {db.x, db.y, db.z, db.w};
        float lc[4][4];
#pragma unroll
        for (int i = 0; i < 4; ++i) {
            const int t = t0 + tm + i;
#pragma unroll
            for (int j = 0; j < 4; ++j) {
                const int s = s0 + tn4 + j;
                const float lv = w_std * m1c[i][j] + w_rec * m2c[i][j] + w_disc * dbv[j];
                lc[i][j] = (s >= t - WIN) ? lv : -1e30f;
            }
        }
        // online softmax (4 own cols + 16 col-groups)
#pragma unroll
        for (int i = 0; i < 4; ++i) {
            float cmx = fmaxf(fmaxf(lc[i][0], lc[i][1]), fmaxf(lc[i][2], lc[i][3]));
#pragma unroll
            for (int off = 1; off < 16; off <<= 1) cmx = fmaxf(cmx, __shfl_xor(cmx, off));
            const float nm = fmaxf(rm[i], cmx);
            const float f = __expf(rm[i] - nm);
            float cs = 0.f;
#pragma unroll
            for (int j = 0; j < 4; ++j) {
                const float p = __expf(lc[i][j] - nm);
                lc[i][j] = p;
                cs += p;
            }
#pragma unroll
            for (int off = 1; off < 16; off <<= 1) cs += __shfl_xor(cs, off);
            rden[i] = rden[i] * f + cs;
            rm[i] = nm;
#pragma unroll
            for (int j = 0; j < 4; ++j) acc[i][j] *= f;
            if (cg == 0) cmf[0][tm + i] = nm;
            float* prow = &Pb[((size_t)(h * T_LEN + t0 + tm + i)) * PBW];
            *(float4*)&prow[tn4] = make_float4(lc[i][0], lc[i][1], lc[i][2], lc[i][3]);
        }
        __syncthreads();   // M2 reads of Bc done
        // scatter P^T into Bc[s_local][m]
#pragma unroll
        for (int j = 0; j < 4; ++j)
            *(float4*)&Bc[tn4 + j][tm] = make_float4(lc[0][j], lc[1][j], lc[2][j], lc[3][j]);
        __syncthreads();
        // ctx += P @ V (64-deep), V from global
#pragma unroll 8
        for (int k = 0; k < 64; ++k) {
            const float4 av = *(const float4*)&Bc[k][tm];
            const float4 bv = *(const float4*)&V[(size_t)(s0 + k) * EMB + h * HD + tn4];
            acc[0][0] += av.x * bv.x; acc[0][1] += av.x * bv.y; acc[0][2] += av.x * bv.z; acc[0][3] += av.x * bv.w;
            acc[1][0] += av.y * bv.x; acc[1][1] += av.y * bv.y; acc[1][2] += av.y * bv.z; acc[1][3] += av.y * bv.w;
            acc[2][0] += av.z * bv.x; acc[2][1] += av.z * bv.y; acc[2][2] += av.z * bv.z; acc[2][3] += av.z * bv.w;
            acc[3][0] += av.w * bv.x; acc[3][1] += av.w * bv.y; acc[3][2] += av.w * bv.z; acc[3][3] += av.w * bv.w;
        }
    }

    // ======== 4 pair-chunks: pair p covers [t0-448+128p, t0-320+128p) ========
    const int p_start = (t0 > 320) ? 0 : (((320 - t0) >> 7) + 1);
    int s0 = t0 - 448 + (p_start << 7);   // >= -64, multiple of 64

    // prefetch first K-pair
    float4 kr[8], qr[8];
    {
        int srow = s0 + sr; srow = srow < 0 ? 0 : srow;
        const float* Kp = K + (size_t)srow * EMB + h * HD + sc;
#pragma unroll
        for (int c = 0; c < 8; ++c) kr[c] = *(const float4*)(Kp + 4 * c);
    }

    for (int cp = p_start; cp < 4; ++cp) {
        __syncthreads();   // b1: prev PV reads of Bp done (and tile staging visible if no chunk)
        // write K-pair transposed [k][s_loc]
#pragma unroll
        for (int c = 0; c < 8; ++c) {
            Bc[sc + 4 * c + 0][sr] = kr[c].x;
            Bc[sc + 4 * c + 1][sr] = kr[c].y;
            Bc[sc + 4 * c + 2][sr] = kr[c].z;
            Bc[sc + 4 * c + 3][sr] = kr[c].w;
        }
        __syncthreads();   // b2

        // issue Q-pair loads (current pair); latency hides under M1
        {
            int srow = s0 + sr; srow = srow < 0 ? 0 : srow;
            const float* Qp = Q + (size_t)srow * EMB + h * HD + sc;
#pragma unroll
            for (int c = 0; c < 8; ++c) qr[c] = *(const float4*)(Qp + 4 * c);
        }

        // M1[i][j] = Q[t0+tm+i] . K[s0 + col(j)]
        float m1[4][8] = {};
#pragma unroll 8
        for (int k = 0; k < 64; ++k) {
            const float4 a4 = *(const float4*)&QT[k][tm];
            const float4 b0 = *(const float4*)&Bc[k][tn4];
            const float4 b1 = *(const float4*)&Bc[k][tn4 + 64];
            const float av[4] = {a4.x, a4.y, a4.z, a4.w};
            const float bv[8] = {b0.x, b0.y, b0.z, b0.w, b1.x, b1.y, b1.z, b1.w};
#pragma unroll
            for (int i = 0; i < 4; ++i)
#pragma unroll
                for (int j = 0; j < 8; ++j)
                    m1[i][j] += av[i] * bv[j];
        }
        __syncthreads();   // b3

        // write Q-pair transposed
#pragma unroll
        for (int c = 0; c < 8; ++c) {
            Bc[sc + 4 * c + 0][sr] = qr[c].x;
            Bc[sc + 4 * c + 1][sr] = qr[c].y;
            Bc[sc + 4 * c + 2][sr] = qr[c].z;
            Bc[sc + 4 * c + 3][sr] = qr[c].w;
        }
        __syncthreads();   // b4

        // issue next K-pair loads; latency hides under M2+PV
        if (cp < 3) {
            int srow = s0 + 128 + sr; srow = srow < 0 ? 0 : srow;
            const float* Kp = K + (size_t)srow * EMB + h * HD + sc;
#pragma unroll
            for (int c = 0; c < 8; ++c) kr[c] = *(const float4*)(Kp + 4 * c);
        }

        // M2[i][j] = K[t0+tm+i] . Q[s0 + col(j)]
        float m2[4][8] = {};
#pragma unroll 8
        for (int k = 0; k < 64; ++k) {
            const float4 a4 = *(const float4*)&KT[k][tm];
            const float4 b0 = *(const float4*)&Bc[k][tn4];
            const float4 b1 = *(const float4*)&Bc[k][tn4 + 64];
            const float av[4] = {a4.x, a4.y, a4.z, a4.w};
            const float bv[8] = {b0.x, b0.y, b0.z, b0.w, b1.x, b1.y, b1.z, b1.w};
#pragma unroll
            for (int i = 0; i < 4; ++i)
#pragma unroll
                for (int j = 0; j < 8; ++j)
                    m2[i][j] += av[i] * bv[j];
        }

        // logits + masks (s can be < 0 for the left-edge pair)
        const int i0 = s0 + tn4;
        const int i0c = i0 < 0 ? 0 : i0;
        const float4 db0 = *(const float4*)&d_bias[h * T_LEN + i0c];
        const float4 db1 = *(const float4*)&d_bias[h * T_LEN + s0 + 64 + tn4];
        const float dbv[8] = {db0.x, db0.y, db0.z, db0.w, db1.x, db1.y, db1.z, db1.w};
        float l[4][8];
#pragma unroll
        for (int i = 0; i < 4; ++i) {
            const int t = t0 + tm + i;
#pragma unroll
            for (int j = 0; j < 8; ++j) {
                const int s = s0 + ((j < 4) ? (tn4 + j) : (tn4 + j + 60));
                const float lv = w_std * m1[i][j] + w_rec * m2[i][j] + w_disc * dbv[j];
                const bool valid = (s >= 0) && (s <= t) && (s >= t - WIN);
                l[i][j] = valid ? lv : -1e30f;
            }
        }
        // online softmax
#pragma unroll
        for (int i = 0; i < 4; ++i) {
            float cmx = fmaxf(fmaxf(fmaxf(l[i][0], l[i][1]), fmaxf(l[i][2], l[i][3])),
                              fmaxf(fmaxf(l[i][4], l[i][5]), fmaxf(l[i][6], l[i][7])));
#pragma unroll
            for (int off = 1; off < 16; off <<= 1) cmx = fmaxf(cmx, __shfl_xor(cmx, off));
            const float nm = fmaxf(rm[i], cmx);
            const float f = __expf(rm[i] - nm);
            float cs = 0.f;
#pragma unroll
            for (int j = 0; j < 8; ++j) {
                const float p = __expf(l[i][j] - nm);
                l[i][j] = p;
                cs += p;
            }
#pragma unroll
            for (int off = 1; off < 16; off <<= 1) cs += __shfl_xor(cs, off);
            rden[i] = rden[i] * f + cs;
            rm[i] = nm;
#pragma unroll
            for (int j = 0; j < 4; ++j) acc[i][j] *= f;
            if (cg == 0) cmf[1 + cp][tm + i] = nm;
            // compact store: Pb col = 64 + 128*cp + local; guard left half when s < 0
            float* prow = &Pb[((size_t)(h * T_LEN + t0 + tm + i)) * PBW + 64 + (cp << 7)];
            if (s0 >= 0)
                *(float4*)&prow[tn4] = make_float4(l[i][0], l[i][1], l[i][2], l[i][3]);
            *(float4*)&prow[64 + tn4] = make_float4(l[i][4], l[i][5], l[i][6], l[i][7]);
        }
        __syncthreads();   // b5

        // scatter P^T into Bp[k][m] as float4 (k = s-local col)
#pragma unroll
        for (int j = 0; j < 4; ++j) {
            *(float4*)&Bp[(tn4 + j) * 68 + tm] =
                make_float4(l[0][j], l[1][j], l[2][j], l[3][j]);
            *(float4*)&Bp[(tn4 + j + 64) * 68 + tm] =
                make_float4(l[0][j + 4], l[1][j + 4], l[2][j + 4], l[3][j + 4]);
        }
        __syncthreads();   // b6

        // ctx += P @ V, V straight from global (L1/L2-hot chunk)
#pragma unroll 8
        for (int k = 0; k < 128; ++k) {
            const float4 av = *(const float4*)&Bp[k * 68 + tm];
            int vrow = s0 + k; vrow = vrow < 0 ? 0 : vrow;
            const float4 bv = *(const float4*)&V[(size_t)vrow * EMB + h * HD + tn4];
            acc[0][0] += av.x * bv.x; acc[0][1] += av.x * bv.y; acc[0][2] += av.x * bv.z; acc[0][3] += av.x * bv.w;
            acc[1][0] += av.y * bv.x; acc[1][1] += av.y * bv.y; acc[1][2] += av.y * bv.z; acc[1][3] += av.y * bv.w;
            acc[2][0] += av.z * bv.x; acc[2][1] += av.z * bv.y; acc[2][2] += av.z * bv.z; acc[2][3] += av.z * bv.w;
            acc[3][0] += av.w * bv.x; acc[3][1] += av.w * bv.y; acc[3][2] += av.w * bv.z; acc[3][3] += av.w * bv.w;
        }
        s0 += 128;
    }

    // ---- epilogue: ctx + per-step rescale factors ----
    float idv[4];
#pragma unroll
    for (int i = 0; i < 4; ++i) {
        idv[i] = 1.0f / rden[i];
        *(float4*)&ctx[(size_t)(t0 + tm + i) * EMB + h * HD + tn4] =
            make_float4(acc[i][0] * idv[i], acc[i][1] * idv[i], acc[i][2] * idv[i], acc[i][3] * idv[i]);
    }
    if (cg == 0) {
#pragma unroll
        for (int i = 0; i < 4; ++i) {
            rmf[tm + i] = rm[i];
            idvf[tm + i] = idv[i];
        }
    }
    __syncthreads();
    // Fb[h][t][c] = exp(m_c - m_final) / den; slot 0 = chunk, 1+p = pairs
    for (int idx = tid; idx < 320; idx += 256) {
        const int c = idx >> 6, r = idx & 63;
        const bool live = (c == 0) ? (t0 >= WIN) : ((c - 1) >= p_start);
        const float fct = live ? __expf(cmf[c][r] - rmf[r]) * idvf[r] : 0.f;
        Fb[((size_t)(h * T_LEN + t0 + r)) * 5 + c] = fct;
    }
}

// ---------------- fused: Wo projection (192 blocks) + band expand (12288 blocks).
// Expand writes ONLY the 576-col band window; zeros were streamed by qkv_zero_kernel.
__global__ __launch_bounds__(256) void wo_expand_kernel(const float* __restrict__ Cb,
                                                        const float* __restrict__ Wo,
                                                        float* __restrict__ out,
                                                        const float* __restrict__ Pb,
                                                        const float* __restrict__ Fb,
                                                        float* __restrict__ attn) {
    const int bid = blockIdx.x;
    const int tid = threadIdx.x;
    if (bid < 192) {
        const int bm = (bid / 6) * GBM;
        const int bn = (bid % 6) * GBN;
        gemm_128(Cb, Wo, out, bm, bn, tid);
    } else {
        const int e = bid - 192;               // 0..12287
        const int h = e / 1024;
        const int t = ((e % 1024) << 2) + (tid >> 6);   // 4 rows per block
        const int ln = tid & 63;
        const int base = (t & ~63) - WIN;      // col = base + j
        const int j_lo = (base < 0) ? -base : 0;   // mult of 64
        const float* prow = Pb + ((size_t)(h * T_LEN + t)) * PBW;
        const float* frow = Fb + ((size_t)(h * T_LEN + t)) * 5;
        const float f0 = frow[0], f1 = frow[1], f2 = frow[2], f3 = frow[3], f4 = frow[4];
        float* arow = attn + ((size_t)(h * T_LEN + t)) * T_LEN;
        for (int j4 = j_lo + (ln << 2); j4 < PBW; j4 += 256) {
            const float4 p = *(const float4*)&prow[j4];
            const float ff = (j4 < 64) ? f0 : (j4 < 192) ? f1 : (j4 < 320) ? f2
                           : (j4 < 448) ? f3 : f4;
            *(float4*)&arow[base + j4] = make_float4(p.x * ff, p.y * ff, p.z * ff, p.w * ff);
        }
    }
}

extern "C" void kernel_launch(void* const* d_in, const int* in_sizes, int n_in,
                              void* d_out, int out_size, void* d_ws, size_t ws_size,
                              hipStream_t stream) {
    const float* x     = (const float*)d_in[0];
    const float* Wq    = (const float*)d_in[1];
    const float* Wk    = (const float*)d_in[2];
    const float* Wv    = (const float*)d_in[3];
    const float* Wo    = (const float*)d_in[4];
    const float* gates = (const float*)d_in[5];
    const float* u     = (const float*)d_in[6];

    float* out  = (float*)d_out;                       // [T, E]
    float* attn = out + (size_t)T_LEN * EMB;           // [H, T, T]

    float* ws = (float*)d_ws;
    float* Qb = ws;
    float* Kb = Qb + (size_t)T_LEN * EMB;
    float* Vb = Kb + (size_t)T_LEN * EMB;
    float* Cb = Vb + (size_t)T_LEN * EMB;
    float* Db = Cb + (size_t)T_LEN * EMB;              // d bias [H, T]
    float* Pb = Db + (size_t)NH * T_LEN;               // compact band p [H, T, 576]
    float* Fb = Pb + (size_t)NH * T_LEN * PBW;         // per-step factors [H, T, 5]

    // QKV projections + out-of-band zero streaming + dbias, all in one launch
    qkv_zero_kernel<<<780, 256, 0, stream>>>(x, Wq, Wk, Wv, u, Qb, Kb, Vb, attn, Db);

    attn_band_kernel<<<dim3(T_LEN / 64, NH), 256, 0, stream>>>(Qb, Kb, Vb, Db, gates,
                                                               Pb, Fb, Cb);

    // Wo projection + band expand, overlapped in one launch
    wo_expand_kernel<<<192 + 12288, 256, 0, stream>>>(Cb, Wo, out, Pb, Fb, attn);
}